// Round 10
// baseline (413.372 us; speedup 1.0000x reference)
//
#include <hip/hip_runtime.h>
#include <hip/hip_bf16.h>

typedef __attribute__((ext_vector_type(8))) short bf16x8;
typedef __attribute__((ext_vector_type(4))) float f32x4;

#define NROWS 262144
#define MBLK  64
#define NBLKS (NROWS / MBLK)   /* 4096 */

// ---------------------------------------------------------------------------
// Weight prep (same layout as R9): B-fragment keyed by (wave, gate, kk):
//   elem (w, g, kk, lane, j) = Wbig[g][n = w*16 + (lane&15)]
//                                   [k = kk*32 + (lane>>4)*8 + j]
// ---------------------------------------------------------------------------
__global__ void prep_weights(
    const float* __restrict__ Wi, const float* __restrict__ Ui,
    const float* __restrict__ Wf, const float* __restrict__ Uf,
    const float* __restrict__ Wo, const float* __restrict__ Uo,
    const float* __restrict__ Wz, const float* __restrict__ Uz,
    ushort* __restrict__ hi, ushort* __restrict__ lo)
{
    int idx = blockIdx.x * 256 + threadIdx.x;   // 0..131071
    int j    = idx & 7;
    int lane = (idx >> 3) & 63;
    int kk   = (idx >> 9) & 7;
    int g    = (idx >> 12) & 3;
    int w    = (idx >> 14) & 7;
    int n = w * 16 + (lane & 15);
    int k = kk * 32 + (lane >> 4) * 8 + j;
    const float* W; const float* U;
    if (g == 0)      { W = Wi; U = Ui; }
    else if (g == 1) { W = Wf; U = Uf; }
    else if (g == 2) { W = Wo; U = Uo; }
    else             { W = Wz; U = Uz; }
    float v = (k < 128) ? W[n * 128 + k] : U[n * 128 + (k - 128)];
    __hip_bfloat16 hb = __float2bfloat16(v);
    float r = v - __bfloat162float(hb);
    __hip_bfloat16 lb = __float2bfloat16(r);
    hi[idx] = *reinterpret_cast<ushort*>(&hb);
    lo[idx] = *reinterpret_cast<ushort*>(&lb);
}

// ---------------------------------------------------------------------------
// Main fused kernel. 4096 blocks; 512 thr = 8 waves; MBLK=64 rows/block.
// Wave w owns cols [16w,16w+16) for ALL 4 gates across 64 rows:
// acc[4][4] = 64 regs; in-register gating (no LDS exchange, 1 barrier).
// Each 1KB B-fragment load now feeds 64 output rows (vs 32 in R9):
// B L2-traffic halves to 2.15 GB. launch_bounds(512,3) (~170-reg cap)
// leaves ~100 arch VGPRs for deep B-load pipelining without spills.
// ---------------------------------------------------------------------------
__global__ __launch_bounds__(512, 3) void slstm_main(
    const float* __restrict__ x,     const float* __restrict__ hprev,
    const float* __restrict__ cprev, const float* __restrict__ nprev,
    const float* __restrict__ bi,    const float* __restrict__ bfg,
    const float* __restrict__ bo,    const float* __restrict__ bz,
    const ushort* __restrict__ whi,  const ushort* __restrict__ wlo,
    float* __restrict__ out)
{
    __shared__ ushort Ahi[64 * 256];   // 32 KB, swizzled bf16-hi of [x|h]
    __shared__ ushort Alo[64 * 256];   // 32 KB, swizzled bf16-lo
    char* AhiB = reinterpret_cast<char*>(Ahi);
    char* AloB = reinterpret_cast<char*>(Alo);

    const int tid  = threadIdx.x;
    const int row0 = blockIdx.x * MBLK;

    // ---- stage A: fp32 loads, split to bf16 hi+lo, swizzled LDS ----
    #pragma unroll
    for (int i = 0; i < 4; ++i) {
        int f4  = tid + i * 512;          // 0..2047
        int row = f4 >> 5;                // 0..63
        int c4  = f4 & 31;
        f32x4 vx = reinterpret_cast<const f32x4*>(x)[(size_t)(row0 + row) * 32 + c4];
        f32x4 vh = reinterpret_cast<const f32x4*>(hprev)[(size_t)(row0 + row) * 32 + c4];
        #pragma unroll
        for (int half = 0; half < 2; ++half) {
            f32x4 v = half ? vh : vx;
            int kbase = half * 128 + 4 * c4;
            int q   = kbase >> 3;
            int sub = (kbase & 7) * 2;
            int byt = row * 512 + ((q ^ (row & 7)) << 4) + sub;
            ushort h4[4], l4v[4];
            #pragma unroll
            for (int e = 0; e < 4; ++e) {
                float ve = v[e];
                __hip_bfloat16 hb = __float2bfloat16(ve);
                float r = ve - __bfloat162float(hb);
                __hip_bfloat16 lb = __float2bfloat16(r);
                h4[e]  = *reinterpret_cast<ushort*>(&hb);
                l4v[e] = *reinterpret_cast<ushort*>(&lb);
            }
            uint2 hp, lp;
            hp.x = (uint)h4[0] | ((uint)h4[1] << 16);
            hp.y = (uint)h4[2] | ((uint)h4[3] << 16);
            lp.x = (uint)l4v[0] | ((uint)l4v[1] << 16);
            lp.y = (uint)l4v[2] | ((uint)l4v[3] << 16);
            *reinterpret_cast<uint2*>(AhiB + byt) = hp;
            *reinterpret_cast<uint2*>(AloB + byt) = lp;
        }
    }
    __syncthreads();   // the ONLY barrier

    const int w    = tid >> 6;         // wave id = column group
    const int lane = tid & 63;
    const int l15  = lane & 15;
    const int lg   = lane >> 4;

    // wave-constant B base (this wave's 16-col slice, all gates)
    const ushort* whiW = whi + (size_t)(w * 32) * 512 + lane * 8;
    const ushort* wloW = wlo + (size_t)(w * 32) * 512 + lane * 8;

    // ---- K-loop: 3-term split-precision MFMA; acc[gate][mi] ----
    f32x4 acc[4][4] = {};

    #pragma unroll
    for (int kk = 0; kk < 8; ++kk) {
        bf16x8 ah[4], al[4];
        #pragma unroll
        for (int mi = 0; mi < 4; ++mi) {
            int row = mi * 16 + l15;
            int q   = kk * 4 + lg;
            int byt = row * 512 + ((q ^ (row & 7)) << 4);
            ah[mi] = *reinterpret_cast<const bf16x8*>(AhiB + byt);
            al[mi] = *reinterpret_cast<const bf16x8*>(AloB + byt);
        }
        #pragma unroll
        for (int g = 0; g < 4; ++g) {
            int eoff = (g * 8 + kk) * 512;
            bf16x8 bh = *reinterpret_cast<const bf16x8*>(whiW + eoff);
            bf16x8 bl = *reinterpret_cast<const bf16x8*>(wloW + eoff);
            #pragma unroll
            for (int mi = 0; mi < 4; ++mi)
                acc[g][mi] = __builtin_amdgcn_mfma_f32_16x16x32_bf16(ah[mi], bh, acc[g][mi], 0, 0, 0);
            #pragma unroll
            for (int mi = 0; mi < 4; ++mi)
                acc[g][mi] = __builtin_amdgcn_mfma_f32_16x16x32_bf16(ah[mi], bl, acc[g][mi], 0, 0, 0);
            #pragma unroll
            for (int mi = 0; mi < 4; ++mi)
                acc[g][mi] = __builtin_amdgcn_mfma_f32_16x16x32_bf16(al[mi], bh, acc[g][mi], 0, 0, 0);
        }
    }

    // ---- fully in-register epilogue ----
    const size_t OUTS = (size_t)NROWS * 128;
    const int c = w * 16 + l15;
    const float bic = bi[c], bfc = bfg[c], boc = bo[c], bzc = bz[c];
    const float* cB = cprev + (size_t)row0 * 128 + c;
    const float* nB = nprev + (size_t)row0 * 128 + c;
    float* outB = out + (size_t)row0 * 128 + c;

    #pragma unroll
    for (int mi = 0; mi < 4; ++mi) {
        // c/n loads for this 16-row group (latency overlaps previous
        // group's gating math)
        float cpv[4], npv[4];
        #pragma unroll
        for (int r = 0; r < 4; ++r) {
            int off = (mi * 16 + lg * 4 + r) * 128;
            cpv[r] = cB[off];
            npv[r] = nB[off];
        }
        #pragma unroll
        for (int r = 0; r < 4; ++r) {
            float pit = acc[0][mi][r] + bic;
            float pft = acc[1][mi][r] + bfc;
            float pot = acc[2][mi][r] + boc;
            float pzt = acc[3][mi][r] + bzc;
            float m   = fmaxf(pft, pit);
            float i_t = __expf(pit - m);
            float f_t = __builtin_amdgcn_rcpf(1.0f + __expf(-pft)) + __expf(pft - m);
            float o_t = __builtin_amdgcn_rcpf(1.0f + __expf(-pot));
            float zc  = fminf(fmaxf(pzt, -15.0f), 15.0f);
            float e2  = __expf(2.0f * zc);
            float z_t = (e2 - 1.0f) * __builtin_amdgcn_rcpf(e2 + 1.0f);
            float c_t = f_t * cpv[r] + i_t * z_t;
            float n_t = f_t * npv[r] + i_t;
            float h_t = o_t * c_t * __builtin_amdgcn_rcpf(n_t + 1e-8f);
            int off = (mi * 16 + lg * 4 + r) * 128;
            outB[off]            = h_t;
            outB[OUTS + off]     = c_t;
            outB[2 * OUTS + off] = n_t;
        }
    }
}

extern "C" void kernel_launch(void* const* d_in, const int* in_sizes, int n_in,
                              void* d_out, int out_size, void* d_ws, size_t ws_size,
                              hipStream_t stream) {
    const float* x  = (const float*)d_in[0];
    const float* h  = (const float*)d_in[1];
    const float* cp = (const float*)d_in[2];
    const float* np = (const float*)d_in[3];
    const float* Wi = (const float*)d_in[4];
    const float* Ui = (const float*)d_in[5];
    const float* Wf = (const float*)d_in[6];
    const float* Uf = (const float*)d_in[7];
    const float* Wo = (const float*)d_in[8];
    const float* Uo = (const float*)d_in[9];
    const float* Wz = (const float*)d_in[10];
    const float* Uz = (const float*)d_in[11];
    const float* bi = (const float*)d_in[12];
    const float* bf = (const float*)d_in[13];
    const float* bo = (const float*)d_in[14];
    const float* bz = (const float*)d_in[15];

    ushort* whi = (ushort*)d_ws;                  // 256 KB
    ushort* wlo = whi + 4 * 128 * 256;            // 256 KB

    prep_weights<<<512, 256, 0, stream>>>(Wi, Ui, Wf, Uf, Wo, Uo, Wz, Uz, whi, wlo);
    slstm_main<<<NBLKS, 512, 0, stream>>>(x, h, cp, np, bi, bf, bo, bz, whi, wlo,
                                          (float*)d_out);
}

// Round 11
// 325.417 us; speedup vs baseline: 1.2703x; 1.2703x over previous
//
#include <hip/hip_runtime.h>
#include <hip/hip_bf16.h>

typedef __attribute__((ext_vector_type(8))) short bf16x8;
typedef __attribute__((ext_vector_type(4))) float f32x4;
typedef __attribute__((ext_vector_type(2))) float f32x2;

#define NROWS 262144
#define MBLK  64
#define NBLKS (NROWS / MBLK)   /* 4096 */

// ---------------------------------------------------------------------------
// Weight prep (layout identical to R9/R10): B-fragment keyed by (w9,g,kk):
//   elem = Wbig[g][n = w9*16 + (lane&15)][k = kk*32 + (lane>>4)*8 + j]
//   at offset ((w9*32 + g*8 + kk)*64 + lane)*8 + j.
// Weights use RNE hi/lo split (offline, best precision).
// ---------------------------------------------------------------------------
__global__ void prep_weights(
    const float* __restrict__ Wi, const float* __restrict__ Ui,
    const float* __restrict__ Wf, const float* __restrict__ Uf,
    const float* __restrict__ Wo, const float* __restrict__ Uo,
    const float* __restrict__ Wz, const float* __restrict__ Uz,
    ushort* __restrict__ hi, ushort* __restrict__ lo)
{
    int idx = blockIdx.x * 256 + threadIdx.x;   // 0..131071
    int j    = idx & 7;
    int lane = (idx >> 3) & 63;
    int kk   = (idx >> 9) & 7;
    int g    = (idx >> 12) & 3;
    int w9   = (idx >> 14) & 7;
    int n = w9 * 16 + (lane & 15);
    int k = kk * 32 + (lane >> 4) * 8 + j;
    const float* W; const float* U;
    if (g == 0)      { W = Wi; U = Ui; }
    else if (g == 1) { W = Wf; U = Uf; }
    else if (g == 2) { W = Wo; U = Uo; }
    else             { W = Wz; U = Uz; }
    float v = (k < 128) ? W[n * 128 + k] : U[n * 128 + (k - 128)];
    __hip_bfloat16 hb = __float2bfloat16(v);
    float r = v - __bfloat162float(hb);
    __hip_bfloat16 lb = __float2bfloat16(r);
    hi[idx] = *reinterpret_cast<ushort*>(&hb);
    lo[idx] = *reinterpret_cast<ushort*>(&lb);
}

// ---------------------------------------------------------------------------
// Main fused kernel. 4096 blocks; 1024 thr = 16 waves; MBLK=64 rows.
// Wave w: gp = w&1 (0 -> gates i,f ; 1 -> gates o,z), cs = w>>1 (16 cols).
// acc[2][4] = 32 regs -> no spills at launch_bounds(1024,4).
// B-traffic: 512 KB per 64 rows = 2.1 GB total (L1 wall gone vs MBLK=32).
// Epilogue: o/z waves write {o_t,z_t} as f32x2 to LDS (aliases dead A-tile);
// i/f waves JIT-load c/n in parallel, then gate fully and store. 3 barriers.
// A-staging uses cheap TRUNCATION hi/lo split (bit-ops only).
// ---------------------------------------------------------------------------
__global__ __launch_bounds__(1024, 4) void slstm_main(
    const float* __restrict__ x,     const float* __restrict__ hprev,
    const float* __restrict__ cprev, const float* __restrict__ nprev,
    const float* __restrict__ bi,    const float* __restrict__ bfg,
    const float* __restrict__ bo,    const float* __restrict__ bz,
    const ushort* __restrict__ whi,  const ushort* __restrict__ wlo,
    float* __restrict__ out)
{
    __shared__ uint lds4[16384];                  // 64 KB
    char* AhiB = reinterpret_cast<char*>(lds4);   // 32 KB bf16-hi A (swizzled)
    char* AloB = AhiB + 32768;                    // 32 KB bf16-lo A
    f32x2* oz  = reinterpret_cast<f32x2*>(lds4);  // epilogue alias: [64][128]

    const int tid  = threadIdx.x;
    const int row0 = blockIdx.x * MBLK;

    // ---- stage A: fp32 loads, TRUNCATION split to bf16 hi+lo, swizzled LDS
    #pragma unroll
    for (int i = 0; i < 2; ++i) {
        int f4  = tid + i * 1024;         // 0..2047
        int row = f4 >> 5;                // 0..63
        int c4  = f4 & 31;
        f32x4 vx = reinterpret_cast<const f32x4*>(x)[(size_t)(row0 + row) * 32 + c4];
        f32x4 vh = reinterpret_cast<const f32x4*>(hprev)[(size_t)(row0 + row) * 32 + c4];
        #pragma unroll
        for (int half = 0; half < 2; ++half) {
            f32x4 v = half ? vh : vx;
            int kbase = half * 128 + 4 * c4;
            int q   = kbase >> 3;
            int sub = (kbase & 7) * 2;
            int byt = row * 512 + ((q ^ (row & 7)) << 4) + sub;
            uint a[4], rb[4];
            #pragma unroll
            for (int e = 0; e < 4; ++e) {
                a[e] = __builtin_bit_cast(uint, (float)v[e]);
                float hiF = __builtin_bit_cast(float, a[e] & 0xFFFF0000u);
                float r   = (float)v[e] - hiF;    // exact
                rb[e] = __builtin_bit_cast(uint, r);
            }
            uint2 hp, lp;
            hp.x = (a[0] >> 16)  | (a[1]  & 0xFFFF0000u);
            hp.y = (a[2] >> 16)  | (a[3]  & 0xFFFF0000u);
            lp.x = (rb[0] >> 16) | (rb[1] & 0xFFFF0000u);
            lp.y = (rb[2] >> 16) | (rb[3] & 0xFFFF0000u);
            *reinterpret_cast<uint2*>(AhiB + byt) = hp;
            *reinterpret_cast<uint2*>(AloB + byt) = lp;
        }
    }
    __syncthreads();   // bar 1

    const int w    = tid >> 6;
    const int lane = tid & 63;
    const int gp   = w & 1;            // 0: i,f   1: o,z
    const int cs   = w >> 1;           // col slice 0..7
    const int l15  = lane & 15;
    const int lg   = lane >> 4;

    // wave-constant B base: gates gp*2 / gp*2+1 of col-group cs
    const ushort* whiW = whi + (size_t)(cs * 32 + gp * 16) * 512 + lane * 8;
    const ushort* wloW = wlo + (size_t)(cs * 32 + gp * 16) * 512 + lane * 8;

    // ---- K-loop: 3-term split-precision MFMA; acc[gi][mi] ----
    f32x4 acc[2][4] = {};

    #pragma unroll
    for (int kk = 0; kk < 8; ++kk) {
        bf16x8 ah[4], al[4];
        #pragma unroll
        for (int mi = 0; mi < 4; ++mi) {
            int row = mi * 16 + l15;
            int q   = kk * 4 + lg;
            int byt = row * 512 + ((q ^ (row & 7)) << 4);
            ah[mi] = *reinterpret_cast<const bf16x8*>(AhiB + byt);
            al[mi] = *reinterpret_cast<const bf16x8*>(AloB + byt);
        }
        #pragma unroll
        for (int gi = 0; gi < 2; ++gi) {
            int eoff = (gi * 8 + kk) * 512;
            bf16x8 bh = *reinterpret_cast<const bf16x8*>(whiW + eoff);
            bf16x8 bl = *reinterpret_cast<const bf16x8*>(wloW + eoff);
            #pragma unroll
            for (int mi = 0; mi < 4; ++mi)
                acc[gi][mi] = __builtin_amdgcn_mfma_f32_16x16x32_bf16(ah[mi], bh, acc[gi][mi], 0, 0, 0);
            #pragma unroll
            for (int mi = 0; mi < 4; ++mi)
                acc[gi][mi] = __builtin_amdgcn_mfma_f32_16x16x32_bf16(ah[mi], bl, acc[gi][mi], 0, 0, 0);
            #pragma unroll
            for (int mi = 0; mi < 4; ++mi)
                acc[gi][mi] = __builtin_amdgcn_mfma_f32_16x16x32_bf16(al[mi], bh, acc[gi][mi], 0, 0, 0);
        }
    }

    const int c = cs * 16 + l15;       // output column 0..127
    __syncthreads();   // bar 2: all A-LDS reads done; safe to overwrite as oz

    float cpv[16], npv[16];
    if (gp == 1) {
        // ---- o,z waves: activate and publish to LDS ----
        const float boc = bo[c], bzc = bz[c];
        #pragma unroll
        for (int mi = 0; mi < 4; ++mi)
            #pragma unroll
            for (int r = 0; r < 4; ++r) {
                float pot = acc[0][mi][r] + boc;
                float pzt = acc[1][mi][r] + bzc;
                float o_t = __builtin_amdgcn_rcpf(1.0f + __expf(-pot));
                float zc  = fminf(fmaxf(pzt, -15.0f), 15.0f);
                float e2  = __expf(2.0f * zc);
                float z_t = (e2 - 1.0f) * __builtin_amdgcn_rcpf(e2 + 1.0f);
                int row = mi * 16 + lg * 4 + r;
                f32x2 vv; vv[0] = o_t; vv[1] = z_t;
                oz[row * 128 + c] = vv;
            }
    } else {
        // ---- i,f waves: JIT c/n loads (overlap the o/z VALU phase) ----
        const float* cB = cprev + (size_t)row0 * 128 + c;
        const float* nB = nprev + (size_t)row0 * 128 + c;
        #pragma unroll
        for (int mi = 0; mi < 4; ++mi)
            #pragma unroll
            for (int r = 0; r < 4; ++r) {
                int off = (mi * 16 + lg * 4 + r) * 128;
                cpv[mi * 4 + r] = cB[off];
                npv[mi * 4 + r] = nB[off];
            }
    }
    __syncthreads();   // bar 3: oz ready

    if (gp == 0) {
        const size_t OUTS = (size_t)NROWS * 128;
        const float bic = bi[c], bfc = bfg[c];
        float* outB = out + (size_t)row0 * 128 + c;
        #pragma unroll
        for (int mi = 0; mi < 4; ++mi)
            #pragma unroll
            for (int r = 0; r < 4; ++r) {
                int row = mi * 16 + lg * 4 + r;
                f32x2 ozv = oz[row * 128 + c];
                float pit = acc[0][mi][r] + bic;
                float pft = acc[1][mi][r] + bfc;
                float m   = fmaxf(pft, pit);
                float i_t = __expf(pit - m);
                float f_t = __builtin_amdgcn_rcpf(1.0f + __expf(-pft)) + __expf(pft - m);
                float c_t = f_t * cpv[mi * 4 + r] + i_t * ozv[1];
                float n_t = f_t * npv[mi * 4 + r] + i_t;
                float h_t = ozv[0] * c_t * __builtin_amdgcn_rcpf(n_t + 1e-8f);
                int off = row * 128;
                outB[off]            = h_t;
                outB[OUTS + off]     = c_t;
                outB[2 * OUTS + off] = n_t;
            }
    }
}

extern "C" void kernel_launch(void* const* d_in, const int* in_sizes, int n_in,
                              void* d_out, int out_size, void* d_ws, size_t ws_size,
                              hipStream_t stream) {
    const float* x  = (const float*)d_in[0];
    const float* h  = (const float*)d_in[1];
    const float* cp = (const float*)d_in[2];
    const float* np = (const float*)d_in[3];
    const float* Wi = (const float*)d_in[4];
    const float* Ui = (const float*)d_in[5];
    const float* Wf = (const float*)d_in[6];
    const float* Uf = (const float*)d_in[7];
    const float* Wo = (const float*)d_in[8];
    const float* Uo = (const float*)d_in[9];
    const float* Wz = (const float*)d_in[10];
    const float* Uz = (const float*)d_in[11];
    const float* bi = (const float*)d_in[12];
    const float* bf = (const float*)d_in[13];
    const float* bo = (const float*)d_in[14];
    const float* bz = (const float*)d_in[15];

    ushort* whi = (ushort*)d_ws;                  // 256 KB
    ushort* wlo = whi + 4 * 128 * 256;            // 256 KB

    prep_weights<<<512, 256, 0, stream>>>(Wi, Ui, Wf, Uf, Wo, Uo, Wz, Uz, whi, wlo);
    slstm_main<<<NBLKS, 1024, 0, stream>>>(x, h, cp, np, bi, bf, bo, bz, whi, wlo,
                                           (float*)d_out);
}